// Round 6
// baseline (739.011 us; speedup 1.0000x reference)
//
#include <hip/hip_runtime.h>

// Problem constants (B=4, C=512, G=32, H=W=64)
#define B_   4
#define C_   512
#define G_   32
#define CPG  16          // channels per group
#define N_   4096        // H*W

typedef unsigned short u16;
typedef __attribute__((ext_vector_type(4))) float f32x4;
typedef __attribute__((ext_vector_type(8))) short s16x8;
typedef __attribute__((ext_vector_type(8))) u16   u16x8;
typedef __attribute__((ext_vector_type(4))) u16   u16x4;

__device__ __forceinline__ u16 f2bf(float f) {
    union { float f; unsigned u; } x; x.f = f;
    unsigned r = x.u + 0x7fffu + ((x.u >> 16) & 1u);   // RNE
    return (u16)(r >> 16);
}

// ---------------------------------------------------------------------------
// GroupNorm statistics: one block per (b, g). Writes per-channel scale/shift.
// ---------------------------------------------------------------------------
__global__ __launch_bounds__(256)
void gn_stats_kernel(const float* __restrict__ x,
                     const float* __restrict__ gamma,
                     const float* __restrict__ beta,
                     float* __restrict__ scale,   // [B*C]
                     float* __restrict__ shift)   // [B*C]
{
    int bg = blockIdx.x;            // 0..127
    int b = bg >> 5, g = bg & 31;
    const float* base = x + (size_t)(b * C_ + g * CPG) * N_;
    const int nelem = CPG * N_;     // 65536
    int t = threadIdx.x;

    float s = 0.f, ss = 0.f;
    for (int i = t * 4; i < nelem; i += 256 * 4) {
        float4 v = *reinterpret_cast<const float4*>(base + i);
        s  += v.x + v.y + v.z + v.w;
        ss += v.x * v.x + v.y * v.y + v.z * v.z + v.w * v.w;
    }
    __shared__ float rs[256], rss[256];
    rs[t] = s; rss[t] = ss;
    __syncthreads();
    for (int off = 128; off > 0; off >>= 1) {
        if (t < off) { rs[t] += rs[t + off]; rss[t] += rss[t + off]; }
        __syncthreads();
    }
    __shared__ float mean_s, rstd_s;
    if (t == 0) {
        float mean = rs[0] / (float)nelem;
        float var  = rss[0] / (float)nelem - mean * mean;
        mean_s = mean;
        rstd_s = rsqrtf(var + 1e-6f);
    }
    __syncthreads();
    if (t < CPG) {
        int c = g * CPG + t;
        float sc = gamma[c] * rstd_s;
        scale[b * C_ + c] = sc;
        shift[b * C_ + c] = beta[c] - mean_s * sc;
    }
}

// ---------------------------------------------------------------------------
// Convert the four 512x512 weight matrices to bf16 (same [co][ci] layout).
// ---------------------------------------------------------------------------
__global__ __launch_bounds__(256)
void wcvt_kernel(const float* __restrict__ wq, const float* __restrict__ wk,
                 const float* __restrict__ wv, const float* __restrict__ wo,
                 u16* __restrict__ wqb, u16* __restrict__ wkb,
                 u16* __restrict__ wvb, u16* __restrict__ wob)
{
    int idx = (blockIdx.x * 256 + threadIdx.x) * 4;
    {
        float4 a = *reinterpret_cast<const float4*>(wq + idx);
        u16x4 r = { f2bf(a.x), f2bf(a.y), f2bf(a.z), f2bf(a.w) };
        *reinterpret_cast<u16x4*>(wqb + idx) = r;
    }
    {
        float4 a = *reinterpret_cast<const float4*>(wk + idx);
        u16x4 r = { f2bf(a.x), f2bf(a.y), f2bf(a.z), f2bf(a.w) };
        *reinterpret_cast<u16x4*>(wkb + idx) = r;
    }
    {
        float4 a = *reinterpret_cast<const float4*>(wv + idx);
        u16x4 r = { f2bf(a.x), f2bf(a.y), f2bf(a.z), f2bf(a.w) };
        *reinterpret_cast<u16x4*>(wvb + idx) = r;
    }
    {
        float4 a = *reinterpret_cast<const float4*>(wo + idx);
        u16x4 r = { f2bf(a.x), f2bf(a.y), f2bf(a.z), f2bf(a.w) };
        *reinterpret_cast<u16x4*>(wob + idx) = r;
    }
}

// ---------------------------------------------------------------------------
// GN-apply + transpose + bf16 convert: x[b][c][n] f32 -> nx_t[b][n][c] bf16.
// ---------------------------------------------------------------------------
__global__ __launch_bounds__(256)
void nxt_kernel(const float* __restrict__ x, const float* __restrict__ scale,
                const float* __restrict__ shift, u16* __restrict__ nx_t)
{
    int b  = blockIdx.z;
    int n0 = blockIdx.x * 64, c0 = blockIdx.y * 64;
    const float* xb = x + ((size_t)b * C_ + c0) * N_ + n0;
    u16* ob = nx_t + ((size_t)b * N_ + n0) * C_ + c0;
    int t = threadIdx.x;
    int tx = t & 15, ty = t >> 4;

    __shared__ float tile[64][65];
    #pragma unroll
    for (int r = 0; r < 4; ++r) {
        int c = ty * 4 + r;
        float sc = scale[b * C_ + c0 + c];
        float sh = shift[b * C_ + c0 + c];
        float4 v = *reinterpret_cast<const float4*>(xb + (size_t)c * N_ + tx * 4);
        tile[c][tx * 4 + 0] = v.x * sc + sh;
        tile[c][tx * 4 + 1] = v.y * sc + sh;
        tile[c][tx * 4 + 2] = v.z * sc + sh;
        tile[c][tx * 4 + 3] = v.w * sc + sh;
    }
    __syncthreads();
    int nn = t >> 2, cc0 = (t & 3) * 16;
    u16x8 o0, o1;
    #pragma unroll
    for (int j = 0; j < 8; ++j) o0[j] = f2bf(tile[cc0 + j][nn]);
    #pragma unroll
    for (int j = 0; j < 8; ++j) o1[j] = f2bf(tile[cc0 + 8 + j][nn]);
    *reinterpret_cast<u16x8*>(ob + (size_t)nn * C_ + cc0)     = o0;
    *reinterpret_cast<u16x8*>(ob + (size_t)nn * C_ + cc0 + 8) = o1;
}

// ---------------------------------------------------------------------------
// TN bf16 MFMA GEMM: D[i][j] = sum_k A[i][k] * B[j][k]
// BM x BN tile, BK=64, 4 waves (2x2), 16x16x32 MFMA, global_load_lds staging.
// Granule XOR-swizzle (both-sides, proven r5: bank conflicts = 0).
// EPI: 0 = bf16 out + bias[j]; 1 = bf16 out + bias[i];
//      2 = f32 out * scale + per-row softmax partial stats (max, expsum)
//          written to pstats (stride 32 float2, base pre-offset by caller);
//      3 = f32 out + bias[i] + resid[i][j]; 4 = bf16 out plain.
// ---------------------------------------------------------------------------
template<int BM, int BN, int EPI>
__device__ __forceinline__
void gemm_dev(int i0, int j0,
              const u16* __restrict__ A, const u16* __restrict__ B,
              void* __restrict__ Dp, const float* __restrict__ bias,
              const float* __restrict__ resid,
              int Nn, int K, int lda, int ldb, float scl,
              float2* __restrict__ pstats)
{
    constexpr int WM = BM / 2, WN = BN / 2;   // wave tile
    constexpr int MI = WM / 16, NI = WN / 16; // fragments per wave

    __shared__ u16 As[BM * 64];
    __shared__ u16 Bs[BN * 64];

    const int t  = threadIdx.x;
    const int l  = t & 63;
    const int w  = t >> 6;          // wave 0..3
    const int wr = w >> 1;          // i-half
    const int wc = w & 1;           // j-half

    const int srow = l >> 3;                    // row within 8-row segment
    const int sgr  = ((l & 7) ^ (l >> 3)) * 8;  // swizzled global k-offset (u16)

    const int fr = l & 15;          // fragment row
    const int q  = l >> 4;          // fragment k-quarter

    f32x4 acc[MI][NI];
    #pragma unroll
    for (int a = 0; a < MI; ++a)
        #pragma unroll
        for (int b2 = 0; b2 < NI; ++b2) acc[a][b2] = 0.f;

    for (int k0 = 0; k0 < K; k0 += 64) {
        #pragma unroll
        for (int r = 0; r < BM / 32; ++r) {
            int s = r * 4 + w;      // 8-row segment
            const u16* ga = A + (size_t)(i0 + s * 8 + srow) * lda + (k0 + sgr);
            __builtin_amdgcn_global_load_lds(
                (const __attribute__((address_space(1))) void*)ga,
                (__attribute__((address_space(3))) void*)&As[s * 512], 16, 0, 0);
        }
        #pragma unroll
        for (int r = 0; r < BN / 32; ++r) {
            int s = r * 4 + w;
            const u16* gb = B + (size_t)(j0 + s * 8 + srow) * ldb + (k0 + sgr);
            __builtin_amdgcn_global_load_lds(
                (const __attribute__((address_space(1))) void*)gb,
                (__attribute__((address_space(3))) void*)&Bs[s * 512], 16, 0, 0);
        }
        __syncthreads();

        #pragma unroll
        for (int h = 0; h < 2; ++h) {
            s16x8 af[MI], bfr[NI];
            #pragma unroll
            for (int mi = 0; mi < MI; ++mi) {
                int r = wr * WM + mi * 16 + fr;
                int p = (h * 4 + q) ^ (r & 7);
                af[mi] = *reinterpret_cast<const s16x8*>(&As[r * 64 + p * 8]);
            }
            #pragma unroll
            for (int ni = 0; ni < NI; ++ni) {
                int r = wc * WN + ni * 16 + fr;
                int p = (h * 4 + q) ^ (r & 7);
                bfr[ni] = *reinterpret_cast<const s16x8*>(&Bs[r * 64 + p * 8]);
            }
            #pragma unroll
            for (int mi = 0; mi < MI; ++mi)
                #pragma unroll
                for (int ni = 0; ni < NI; ++ni)
                    acc[mi][ni] = __builtin_amdgcn_mfma_f32_16x16x32_bf16(
                        af[mi], bfr[ni], acc[mi][ni], 0, 0, 0);
        }
        __syncthreads();
    }

    const int orow = (l >> 4) * 4;
    const int ocol = l & 15;
    #pragma unroll
    for (int mi = 0; mi < MI; ++mi) {
        #pragma unroll
        for (int ni = 0; ni < NI; ++ni) {
            int ib = i0 + wr * WM + mi * 16 + orow;
            int jb = j0 + wc * WN + ni * 16 + ocol;
            if constexpr (EPI == 0 || EPI == 1 || EPI == 4) {
                u16* D = (u16*)Dp;
                float bj = 0.f;
                if constexpr (EPI == 0) bj = bias[jb];
                #pragma unroll
                for (int e = 0; e < 4; ++e) {
                    float vv = acc[mi][ni][e];
                    if constexpr (EPI == 0) vv += bj;
                    if constexpr (EPI == 1) vv += bias[ib + e];
                    D[(size_t)(ib + e) * Nn + jb] = f2bf(vv);
                }
            } else if constexpr (EPI == 2) {
                float* D = (float*)Dp;
                #pragma unroll
                for (int e = 0; e < 4; ++e)
                    D[(size_t)(ib + e) * Nn + jb] = acc[mi][ni][e] * scl;
            } else {   // EPI == 3
                float* D = (float*)Dp;
                #pragma unroll
                for (int e = 0; e < 4; ++e)
                    D[(size_t)(ib + e) * Nn + jb] =
                        acc[mi][ni][e] + bias[ib + e] + resid[(size_t)(ib + e) * Nn + jb];
            }
        }
    }

    // ---- fused per-row softmax partial stats (scores only) ----
    if constexpr (EPI == 2) {
        __shared__ float sstm[2][2][64];
        __shared__ float sstl[2][2][64];
        #pragma unroll
        for (int mi = 0; mi < MI; ++mi) {
            #pragma unroll
            for (int e = 0; e < 4; ++e) {
                float vmax = -1e30f;
                #pragma unroll
                for (int ni = 0; ni < NI; ++ni)
                    vmax = fmaxf(vmax, acc[mi][ni][e] * scl);
                #pragma unroll
                for (int m2 = 1; m2 < 16; m2 <<= 1)
                    vmax = fmaxf(vmax, __shfl_xor(vmax, m2));
                float se = 0.f;
                #pragma unroll
                for (int ni = 0; ni < NI; ++ni)
                    se += __expf(acc[mi][ni][e] * scl - vmax);
                #pragma unroll
                for (int m2 = 1; m2 < 16; m2 <<= 1)
                    se += __shfl_xor(se, m2);
                if ((l & 15) == 0) {
                    int r64 = mi * 16 + (l >> 4) * 4 + e;
                    sstm[wr][wc][r64] = vmax;
                    sstl[wr][wc][r64] = se;
                }
            }
        }
        __syncthreads();
        if (t < 128) {
            int wr2 = t >> 6, r = t & 63;
            float m0 = sstm[wr2][0][r], m1 = sstm[wr2][1][r];
            float l0 = sstl[wr2][0][r], l1 = sstl[wr2][1][r];
            float m = fmaxf(m0, m1);
            float ll = l0 * __expf(m0 - m) + l1 * __expf(m1 - m);
            pstats[(size_t)t * 32] = make_float2(m, ll);
        }
    }
}

// q_t/k_t: D[n][co] = sum_ci nx_t[n][ci] * W[co][ci] + b[co].  grid (4,32,8)
__global__ __launch_bounds__(256)
void qk_gemm(const u16* __restrict__ nx_t, const u16* __restrict__ wqb,
             const u16* __restrict__ wkb, const float* __restrict__ bq,
             const float* __restrict__ bk, u16* __restrict__ q_t,
             u16* __restrict__ k_t)
{
    int z = blockIdx.z, b = z & 3, isk = z >> 2;
    gemm_dev<128, 128, 0>(blockIdx.y * 128, blockIdx.x * 128,
                          nx_t + (size_t)b * N_ * C_, isk ? wkb : wqb,
                          (isk ? k_t : q_t) + (size_t)b * N_ * C_,
                          isk ? bk : bq, nullptr, C_, C_, C_, C_, 1.f, nullptr);
}

// v: D[co][n] = sum_ci Wv[co][ci] * nx_t[n][ci] + bv[co].  grid (32,4,4)
__global__ __launch_bounds__(256)
void v_gemm(const u16* __restrict__ wvb, const u16* __restrict__ nx_t,
            const float* __restrict__ bv, u16* __restrict__ vbuf)
{
    int b = blockIdx.z;
    gemm_dev<128, 128, 1>(blockIdx.y * 128, blockIdx.x * 128,
                          wvb, nx_t + (size_t)b * N_ * C_, vbuf + (size_t)b * C_ * N_,
                          bv, nullptr, N_, C_, C_, C_, 1.f, nullptr);
}

// scores: S[z][i][j] = (sum_c q_t[i][c]*k_t[j][c]) / sqrt(C) + partial stats.
// grid (32,32,nb)
__global__ __launch_bounds__(256)
void scores_gemm(const u16* __restrict__ q_t, const u16* __restrict__ k_t,
                 float* __restrict__ S, float2* __restrict__ pstats, int b0)
{
    int z = blockIdx.z, b = b0 + z;
    int i0 = blockIdx.y * 128, j0 = blockIdx.x * 128;
    float2* pst = pstats + ((size_t)b * N_ + i0) * 32 + blockIdx.x;
    gemm_dev<128, 128, 2>(i0, j0,
                          q_t + (size_t)b * N_ * C_, k_t + (size_t)b * N_ * C_,
                          S + (size_t)z * N_ * N_, nullptr, nullptr, N_, C_, C_, C_,
                          0.044194173824159216f, pst);
}

// Combine partial stats -> mh[i] = rowmax + ln(rowsum). grid (nb*16) x 256.
__global__ __launch_bounds__(256)
void stats_combine(const float2* __restrict__ pstats, float* __restrict__ mh,
                   int row0)
{
    int r = row0 + blockIdx.x * 256 + threadIdx.x;
    const float2* p = pstats + (size_t)r * 32;
    float m = -1e30f;
    #pragma unroll
    for (int jt = 0; jt < 32; ++jt) m = fmaxf(m, p[jt].x);
    float l = 0.f;
    #pragma unroll
    for (int jt = 0; jt < 32; ++jt) l += p[jt].y * __expf(p[jt].x - m);
    mh[r] = m + __logf(l);
}

// ---------------------------------------------------------------------------
// Fused softmax+PV: attn_t[i][c] = sum_j exp(S[i][j]-mh[i]) * v[c][j].
// A-fragments built DIRECTLY from fp32 S (L2-resident via swizzle) with
// on-the-fly exp; no A-side LDS. V staged via global_load_lds (XOR swizzle).
// BM=128 i, BN=128 c, BK=64. grid nb*128, XCD-gathering swizzle: the 4
// c-tiles of one (i-tile,z) share an XCD -> S i-tile read from HBM once.
// ---------------------------------------------------------------------------
__global__ __launch_bounds__(256)
void pv_fused(const float* __restrict__ S, const float* __restrict__ mh,
              const u16* __restrict__ vbuf, u16* __restrict__ attn_t,
              int b0, int nb)
{
    int id  = blockIdx.x;
    int xcd = id & 7, slot = id >> 3;
    int yz  = xcd * 4 * nb + (slot >> 2);   // (i-tile, z) combo
    int ct  = slot & 3;                     // c-tile 0..3
    int it  = yz & 31, z = yz >> 5;
    int b = b0 + z;
    const float* Sb  = S + (size_t)z * N_ * N_;
    const float* mhb = mh + (size_t)b * N_;
    const u16*   Vb  = vbuf + (size_t)b * C_ * N_;
    u16*         Ob  = attn_t + (size_t)b * N_ * C_;

    const int i0 = it * 128, c0 = ct * 128;
    const int t = threadIdx.x, l = t & 63, w = t >> 6;
    const int wr = w >> 1, wc = w & 1;
    const int srow = l >> 3;
    const int sgr  = ((l & 7) ^ (l >> 3)) * 8;
    const int fr = l & 15, q = l >> 4;

    __shared__ u16 Bs[128 * 64];

    f32x4 acc[4][4];
    #pragma unroll
    for (int a = 0; a < 4; ++a)
        #pragma unroll
        for (int b2 = 0; b2 < 4; ++b2) acc[a][b2] = 0.f;

    const float* srow_p[4];
    float mh_r[4];
    #pragma unroll
    for (int mi = 0; mi < 4; ++mi) {
        int i = i0 + wr * 64 + mi * 16 + fr;
        srow_p[mi] = Sb + (size_t)i * N_;
        mh_r[mi] = mhb[i];
    }

    for (int k0 = 0; k0 < N_; k0 += 64) {
        // V staging (async, flies under the exp work below)
        #pragma unroll
        for (int r = 0; r < 4; ++r) {
            int s = r * 4 + w;
            const u16* gb = Vb + (size_t)(c0 + s * 8 + srow) * N_ + (k0 + sgr);
            __builtin_amdgcn_global_load_lds(
                (const __attribute__((address_space(1))) void*)gb,
                (__attribute__((address_space(3))) void*)&Bs[s * 512], 16, 0, 0);
        }
        // A fragments: P = exp(S - mh), fp32 -> bf16, straight into registers
        s16x8 af[2][4];
        #pragma unroll
        for (int h = 0; h < 2; ++h) {
            #pragma unroll
            for (int mi = 0; mi < 4; ++mi) {
                const float* sp = srow_p[mi] + k0 + h * 32 + q * 8;
                float4 a0 = *reinterpret_cast<const float4*>(sp);
                float4 a1 = *reinterpret_cast<const float4*>(sp + 4);
                float mhv = mh_r[mi];
                s16x8 pk;
                pk[0] = (short)f2bf(__expf(a0.x - mhv));
                pk[1] = (short)f2bf(__expf(a0.y - mhv));
                pk[2] = (short)f2bf(__expf(a0.z - mhv));
                pk[3] = (short)f2bf(__expf(a0.w - mhv));
                pk[4] = (short)f2bf(__expf(a1.x - mhv));
                pk[5] = (short)f2bf(__expf(a1.y - mhv));
                pk[6] = (short)f2bf(__expf(a1.z - mhv));
                pk[7] = (short)f2bf(__expf(a1.w - mhv));
                af[h][mi] = pk;
            }
        }
        __syncthreads();
        #pragma unroll
        for (int h = 0; h < 2; ++h) {
            s16x8 bfr[4];
            #pragma unroll
            for (int ni = 0; ni < 4; ++ni) {
                int r = wc * 64 + ni * 16 + fr;
                int p = (h * 4 + q) ^ (r & 7);
                bfr[ni] = *reinterpret_cast<const s16x8*>(&Bs[r * 64 + p * 8]);
            }
            #pragma unroll
            for (int mi = 0; mi < 4; ++mi)
                #pragma unroll
                for (int ni = 0; ni < 4; ++ni)
                    acc[mi][ni] = __builtin_amdgcn_mfma_f32_16x16x32_bf16(
                        af[h][mi], bfr[ni], acc[mi][ni], 0, 0, 0);
        }
        __syncthreads();
    }

    const int orow = (l >> 4) * 4;
    const int ocol = l & 15;
    #pragma unroll
    for (int mi = 0; mi < 4; ++mi) {
        #pragma unroll
        for (int ni = 0; ni < 4; ++ni) {
            int ib = i0 + wr * 64 + mi * 16 + orow;
            int jb = c0 + wc * 64 + ni * 16 + ocol;
            #pragma unroll
            for (int e = 0; e < 4; ++e)
                Ob[(size_t)(ib + e) * C_ + jb] = f2bf(acc[mi][ni][e]);
        }
    }
}

// final: out[co][n] = x + bo[co] + sum_ci wo[co][ci]*attn_t[n][ci]. grid (32,4,4)
__global__ __launch_bounds__(256)
void final_gemm(const u16* __restrict__ wob, const u16* __restrict__ attn_t,
                const float* __restrict__ bo, const float* __restrict__ x,
                float* __restrict__ outp)
{
    int b = blockIdx.z;
    gemm_dev<128, 128, 3>(blockIdx.y * 128, blockIdx.x * 128,
                          wob, attn_t + (size_t)b * N_ * C_, outp + (size_t)b * C_ * N_,
                          bo, x + (size_t)b * C_ * N_, N_, C_, C_, C_, 1.f, nullptr);
}

// ---------------------------------------------------------------------------
extern "C" void kernel_launch(void* const* d_in, const int* in_sizes, int n_in,
                              void* d_out, int out_size, void* d_ws, size_t ws_size,
                              hipStream_t stream)
{
    const float* x     = (const float*)d_in[0];
    const float* gamma = (const float*)d_in[1];
    const float* beta  = (const float*)d_in[2];
    const float* wq    = (const float*)d_in[3];
    const float* bq    = (const float*)d_in[4];
    const float* wk    = (const float*)d_in[5];
    const float* bk    = (const float*)d_in[6];
    const float* wv    = (const float*)d_in[7];
    const float* bv    = (const float*)d_in[8];
    const float* wo    = (const float*)d_in[9];
    const float* bo    = (const float*)d_in[10];
    float* out = (float*)d_out;

    // Workspace carve. Base ~70 MB + pstats 4 MB + mh + S buffers (67 MB each).
    char* p = (char*)d_ws;
    auto take = [&](size_t bytes) { char* r = p; p += (bytes + 255) & ~(size_t)255; return r; };
    float* scale = (float*)take(B_ * C_ * 4);
    float* shift = (float*)take(B_ * C_ * 4);
    u16* wqb = (u16*)take((size_t)C_ * C_ * 2);
    u16* wkb = (u16*)take((size_t)C_ * C_ * 2);
    u16* wvb = (u16*)take((size_t)C_ * C_ * 2);
    u16* wob = (u16*)take((size_t)C_ * C_ * 2);
    u16* nx_t  = (u16*)take((size_t)B_ * N_ * C_ * 2);   // reused as attn_t
    u16* q_t   = (u16*)take((size_t)B_ * N_ * C_ * 2);
    u16* k_t   = (u16*)take((size_t)B_ * N_ * C_ * 2);
    u16* vbuf  = (u16*)take((size_t)B_ * C_ * N_ * 2);
    float2* pstats = (float2*)take((size_t)B_ * N_ * 32 * 8);
    float*  mh     = (float*)take((size_t)B_ * N_ * 4);
    size_t base_used = (size_t)(p - (char*)d_ws);
    size_t s_bytes = (size_t)N_ * N_ * 4;
    bool four = ws_size >= base_used + 4 * s_bytes + 1024;
    float* S = (float*)take(s_bytes * (four ? 4 : 2));
    u16* attn_t = nx_t;    // nx_t is dead after qkv projections

    gn_stats_kernel<<<128, 256, 0, stream>>>(x, gamma, beta, scale, shift);
    wcvt_kernel<<<256, 256, 0, stream>>>(wq, wk, wv, wo, wqb, wkb, wvb, wob);
    nxt_kernel<<<dim3(N_ / 64, C_ / 64, B_), 256, 0, stream>>>(x, scale, shift, nx_t);

    qk_gemm<<<dim3(C_ / 128, N_ / 128, 8), 256, 0, stream>>>(nx_t, wqb, wkb, bq, bk, q_t, k_t);
    v_gemm<<<dim3(N_ / 128, C_ / 128, B_), 256, 0, stream>>>(wvb, nx_t, bv, vbuf);

    if (four) {
        scores_gemm<<<dim3(N_ / 128, N_ / 128, 4), 256, 0, stream>>>(q_t, k_t, S, pstats, 0);
        stats_combine<<<4 * 16, 256, 0, stream>>>(pstats, mh, 0);
        pv_fused<<<4 * 128, 256, 0, stream>>>(S, mh, vbuf, attn_t, 0, 4);
    } else {
        for (int pair = 0; pair < 2; ++pair) {
            scores_gemm<<<dim3(N_ / 128, N_ / 128, 2), 256, 0, stream>>>(q_t, k_t, S, pstats, pair * 2);
            stats_combine<<<2 * 16, 256, 0, stream>>>(pstats, mh, pair * 2 * N_);
            pv_fused<<<2 * 128, 256, 0, stream>>>(S, mh, vbuf, attn_t, pair * 2, 2);
        }
    }

    final_gemm<<<dim3(N_ / 128, C_ / 128, B_), 256, 0, stream>>>(wob, attn_t, bo, x, out);
}

// Round 8
// 363.767 us; speedup vs baseline: 2.0315x; 2.0315x over previous
//
#include <hip/hip_runtime.h>

// Problem constants (B=4, C=512, G=32, H=W=64)
#define B_   4
#define C_   512
#define G_   32
#define CPG  16          // channels per group
#define N_   4096        // H*W

typedef unsigned short u16;
typedef __attribute__((ext_vector_type(4))) float f32x4;
typedef __attribute__((ext_vector_type(8))) short s16x8;
typedef __attribute__((ext_vector_type(8))) u16   u16x8;
typedef __attribute__((ext_vector_type(4))) u16   u16x4;

__device__ __forceinline__ u16 f2bf(float f) {
    union { float f; unsigned u; } x; x.f = f;
    unsigned r = x.u + 0x7fffu + ((x.u >> 16) & 1u);   // RNE
    return (u16)(r >> 16);
}

// ---------------------------------------------------------------------------
// GroupNorm statistics: one block per (b, g). Writes per-channel scale/shift.
// ---------------------------------------------------------------------------
__global__ __launch_bounds__(256)
void gn_stats_kernel(const float* __restrict__ x,
                     const float* __restrict__ gamma,
                     const float* __restrict__ beta,
                     float* __restrict__ scale,   // [B*C]
                     float* __restrict__ shift)   // [B*C]
{
    int bg = blockIdx.x;            // 0..127
    int b = bg >> 5, g = bg & 31;
    const float* base = x + (size_t)(b * C_ + g * CPG) * N_;
    const int nelem = CPG * N_;     // 65536
    int t = threadIdx.x;

    float s = 0.f, ss = 0.f;
    for (int i = t * 4; i < nelem; i += 256 * 4) {
        float4 v = *reinterpret_cast<const float4*>(base + i);
        s  += v.x + v.y + v.z + v.w;
        ss += v.x * v.x + v.y * v.y + v.z * v.z + v.w * v.w;
    }
    __shared__ float rs[256], rss[256];
    rs[t] = s; rss[t] = ss;
    __syncthreads();
    for (int off = 128; off > 0; off >>= 1) {
        if (t < off) { rs[t] += rs[t + off]; rss[t] += rss[t + off]; }
        __syncthreads();
    }
    __shared__ float mean_s, rstd_s;
    if (t == 0) {
        float mean = rs[0] / (float)nelem;
        float var  = rss[0] / (float)nelem - mean * mean;
        mean_s = mean;
        rstd_s = rsqrtf(var + 1e-6f);
    }
    __syncthreads();
    if (t < CPG) {
        int c = g * CPG + t;
        float sc = gamma[c] * rstd_s;
        scale[b * C_ + c] = sc;
        shift[b * C_ + c] = beta[c] - mean_s * sc;
    }
}

// ---------------------------------------------------------------------------
// Convert the four 512x512 weight matrices to bf16 (same [co][ci] layout).
// ---------------------------------------------------------------------------
__global__ __launch_bounds__(256)
void wcvt_kernel(const float* __restrict__ wq, const float* __restrict__ wk,
                 const float* __restrict__ wv, const float* __restrict__ wo,
                 u16* __restrict__ wqb, u16* __restrict__ wkb,
                 u16* __restrict__ wvb, u16* __restrict__ wob)
{
    int idx = (blockIdx.x * 256 + threadIdx.x) * 4;
    {
        float4 a = *reinterpret_cast<const float4*>(wq + idx);
        u16x4 r = { f2bf(a.x), f2bf(a.y), f2bf(a.z), f2bf(a.w) };
        *reinterpret_cast<u16x4*>(wqb + idx) = r;
    }
    {
        float4 a = *reinterpret_cast<const float4*>(wk + idx);
        u16x4 r = { f2bf(a.x), f2bf(a.y), f2bf(a.z), f2bf(a.w) };
        *reinterpret_cast<u16x4*>(wkb + idx) = r;
    }
    {
        float4 a = *reinterpret_cast<const float4*>(wv + idx);
        u16x4 r = { f2bf(a.x), f2bf(a.y), f2bf(a.z), f2bf(a.w) };
        *reinterpret_cast<u16x4*>(wvb + idx) = r;
    }
    {
        float4 a = *reinterpret_cast<const float4*>(wo + idx);
        u16x4 r = { f2bf(a.x), f2bf(a.y), f2bf(a.z), f2bf(a.w) };
        *reinterpret_cast<u16x4*>(wob + idx) = r;
    }
}

// ---------------------------------------------------------------------------
// GN-apply + transpose + bf16 convert: x[b][c][n] f32 -> nx_t[b][n][c] bf16.
// ---------------------------------------------------------------------------
__global__ __launch_bounds__(256)
void nxt_kernel(const float* __restrict__ x, const float* __restrict__ scale,
                const float* __restrict__ shift, u16* __restrict__ nx_t)
{
    int b  = blockIdx.z;
    int n0 = blockIdx.x * 64, c0 = blockIdx.y * 64;
    const float* xb = x + ((size_t)b * C_ + c0) * N_ + n0;
    u16* ob = nx_t + ((size_t)b * N_ + n0) * C_ + c0;
    int t = threadIdx.x;
    int tx = t & 15, ty = t >> 4;

    __shared__ float tile[64][65];
    #pragma unroll
    for (int r = 0; r < 4; ++r) {
        int c = ty * 4 + r;
        float sc = scale[b * C_ + c0 + c];
        float sh = shift[b * C_ + c0 + c];
        float4 v = *reinterpret_cast<const float4*>(xb + (size_t)c * N_ + tx * 4);
        tile[c][tx * 4 + 0] = v.x * sc + sh;
        tile[c][tx * 4 + 1] = v.y * sc + sh;
        tile[c][tx * 4 + 2] = v.z * sc + sh;
        tile[c][tx * 4 + 3] = v.w * sc + sh;
    }
    __syncthreads();
    int nn = t >> 2, cc0 = (t & 3) * 16;
    u16x8 o0, o1;
    #pragma unroll
    for (int j = 0; j < 8; ++j) o0[j] = f2bf(tile[cc0 + j][nn]);
    #pragma unroll
    for (int j = 0; j < 8; ++j) o1[j] = f2bf(tile[cc0 + 8 + j][nn]);
    *reinterpret_cast<u16x8*>(ob + (size_t)nn * C_ + cc0)     = o0;
    *reinterpret_cast<u16x8*>(ob + (size_t)nn * C_ + cc0 + 8) = o1;
}

// ---------------------------------------------------------------------------
// TN bf16 MFMA GEMM: D[i][j] = sum_k A[i][k] * B[j][k]
// BM x BN tile, BK=64, 4 waves (2x2), 16x16x32 MFMA, global_load_lds staging.
// Granule XOR-swizzle (both-sides, proven r5: bank conflicts = 0).
// EPI: 0 = bf16 out + bias[j]; 1 = bf16 out + bias[i];
//      2 = P_partial path: per-(row, j-tile) max m & expsum l via shuffle
//          reduce -> pstats; then write bf16 exp(acc*scl - m) to Dp;
//      3 = f32 out + bias[i] + resid[i][j]; 4 = bf16 out plain.
// ---------------------------------------------------------------------------
template<int BM, int BN, int EPI>
__device__ __forceinline__
void gemm_dev(int i0, int j0,
              const u16* __restrict__ A, const u16* __restrict__ B,
              void* __restrict__ Dp, const float* __restrict__ bias,
              const float* __restrict__ resid,
              int Nn, int K, int lda, int ldb, float scl,
              float2* __restrict__ pstats)
{
    constexpr int WM = BM / 2, WN = BN / 2;   // wave tile
    constexpr int MI = WM / 16, NI = WN / 16; // fragments per wave

    __shared__ u16 As[BM * 64];
    __shared__ u16 Bs[BN * 64];

    const int t  = threadIdx.x;
    const int l  = t & 63;
    const int w  = t >> 6;          // wave 0..3
    const int wr = w >> 1;          // i-half
    const int wc = w & 1;           // j-half

    const int srow = l >> 3;                    // row within 8-row segment
    const int sgr  = ((l & 7) ^ (l >> 3)) * 8;  // swizzled global k-offset (u16)

    const int fr = l & 15;          // fragment row
    const int q  = l >> 4;          // fragment k-quarter

    f32x4 acc[MI][NI];
    #pragma unroll
    for (int a = 0; a < MI; ++a)
        #pragma unroll
        for (int b2 = 0; b2 < NI; ++b2) acc[a][b2] = 0.f;

    for (int k0 = 0; k0 < K; k0 += 64) {
        #pragma unroll
        for (int r = 0; r < BM / 32; ++r) {
            int s = r * 4 + w;      // 8-row segment
            const u16* ga = A + (size_t)(i0 + s * 8 + srow) * lda + (k0 + sgr);
            __builtin_amdgcn_global_load_lds(
                (const __attribute__((address_space(1))) void*)ga,
                (__attribute__((address_space(3))) void*)&As[s * 512], 16, 0, 0);
        }
        #pragma unroll
        for (int r = 0; r < BN / 32; ++r) {
            int s = r * 4 + w;
            const u16* gb = B + (size_t)(j0 + s * 8 + srow) * ldb + (k0 + sgr);
            __builtin_amdgcn_global_load_lds(
                (const __attribute__((address_space(1))) void*)gb,
                (__attribute__((address_space(3))) void*)&Bs[s * 512], 16, 0, 0);
        }
        __syncthreads();

        #pragma unroll
        for (int h = 0; h < 2; ++h) {
            s16x8 af[MI], bfr[NI];
            #pragma unroll
            for (int mi = 0; mi < MI; ++mi) {
                int r = wr * WM + mi * 16 + fr;
                int p = (h * 4 + q) ^ (r & 7);
                af[mi] = *reinterpret_cast<const s16x8*>(&As[r * 64 + p * 8]);
            }
            #pragma unroll
            for (int ni = 0; ni < NI; ++ni) {
                int r = wc * WN + ni * 16 + fr;
                int p = (h * 4 + q) ^ (r & 7);
                bfr[ni] = *reinterpret_cast<const s16x8*>(&Bs[r * 64 + p * 8]);
            }
            #pragma unroll
            for (int mi = 0; mi < MI; ++mi)
                #pragma unroll
                for (int ni = 0; ni < NI; ++ni)
                    acc[mi][ni] = __builtin_amdgcn_mfma_f32_16x16x32_bf16(
                        af[mi], bfr[ni], acc[mi][ni], 0, 0, 0);
        }
        __syncthreads();
    }

    const int orow = (l >> 4) * 4;
    const int ocol = l & 15;

    if constexpr (EPI != 2) {
        #pragma unroll
        for (int mi = 0; mi < MI; ++mi) {
            #pragma unroll
            for (int ni = 0; ni < NI; ++ni) {
                int ib = i0 + wr * WM + mi * 16 + orow;
                int jb = j0 + wc * WN + ni * 16 + ocol;
                if constexpr (EPI == 0 || EPI == 1 || EPI == 4) {
                    u16* D = (u16*)Dp;
                    float bj = 0.f;
                    if constexpr (EPI == 0) bj = bias[jb];
                    #pragma unroll
                    for (int e = 0; e < 4; ++e) {
                        float vv = acc[mi][ni][e];
                        if constexpr (EPI == 0) vv += bj;
                        if constexpr (EPI == 1) vv += bias[ib + e];
                        D[(size_t)(ib + e) * Nn + jb] = f2bf(vv);
                    }
                } else {   // EPI == 3
                    float* D = (float*)Dp;
                    #pragma unroll
                    for (int e = 0; e < 4; ++e)
                        D[(size_t)(ib + e) * Nn + jb] =
                            acc[mi][ni][e] + bias[ib + e] + resid[(size_t)(ib + e) * Nn + jb];
                }
            }
        }
    } else {
        // ---- P_partial path: stats, then bf16 exp write ----
        __shared__ float sstm[2][2][64];
        __shared__ float sstl[2][2][64];
        __shared__ float mcomb[2][64];
        #pragma unroll
        for (int mi = 0; mi < MI; ++mi) {
            #pragma unroll
            for (int e = 0; e < 4; ++e) {
                float vmax = -1e30f;
                #pragma unroll
                for (int ni = 0; ni < NI; ++ni)
                    vmax = fmaxf(vmax, acc[mi][ni][e] * scl);
                #pragma unroll
                for (int m2 = 1; m2 < 16; m2 <<= 1)
                    vmax = fmaxf(vmax, __shfl_xor(vmax, m2));
                float se = 0.f;
                #pragma unroll
                for (int ni = 0; ni < NI; ++ni)
                    se += __expf(acc[mi][ni][e] * scl - vmax);
                #pragma unroll
                for (int m2 = 1; m2 < 16; m2 <<= 1)
                    se += __shfl_xor(se, m2);
                if ((l & 15) == 0) {
                    int r64 = mi * 16 + (l >> 4) * 4 + e;
                    sstm[wr][wc][r64] = vmax;
                    sstl[wr][wc][r64] = se;
                }
            }
        }
        __syncthreads();
        if (t < 128) {
            int wr2 = t >> 6, r = t & 63;
            float m0 = sstm[wr2][0][r], m1 = sstm[wr2][1][r];
            float l0 = sstl[wr2][0][r], l1 = sstl[wr2][1][r];
            float m = fmaxf(m0, m1);
            float ll = l0 * __expf(m0 - m) + l1 * __expf(m1 - m);
            pstats[(size_t)t * 32] = make_float2(m, ll);
            mcomb[wr2][r] = m;
        }
        __syncthreads();
        u16* D = (u16*)Dp;
        #pragma unroll
        for (int mi = 0; mi < MI; ++mi) {
            #pragma unroll
            for (int ni = 0; ni < NI; ++ni) {
                int ib = i0 + wr * WM + mi * 16 + orow;
                int jb = j0 + wc * WN + ni * 16 + ocol;
                #pragma unroll
                for (int e = 0; e < 4; ++e) {
                    float m = mcomb[wr][mi * 16 + orow + e];
                    D[(size_t)(ib + e) * Nn + jb] =
                        f2bf(__expf(acc[mi][ni][e] * scl - m));
                }
            }
        }
    }
}

// q_t/k_t: D[n][co] = sum_ci nx_t[n][ci] * W[co][ci] + b[co].  grid (4,32,8)
__global__ __launch_bounds__(256)
void qk_gemm(const u16* __restrict__ nx_t, const u16* __restrict__ wqb,
             const u16* __restrict__ wkb, const float* __restrict__ bq,
             const float* __restrict__ bk, u16* __restrict__ q_t,
             u16* __restrict__ k_t)
{
    int z = blockIdx.z, b = z & 3, isk = z >> 2;
    gemm_dev<128, 128, 0>(blockIdx.y * 128, blockIdx.x * 128,
                          nx_t + (size_t)b * N_ * C_, isk ? wkb : wqb,
                          (isk ? k_t : q_t) + (size_t)b * N_ * C_,
                          isk ? bk : bq, nullptr, C_, C_, C_, C_, 1.f, nullptr);
}

// v: D[co][n] = sum_ci Wv[co][ci] * nx_t[n][ci] + bv[co].  grid (32,4,4)
__global__ __launch_bounds__(256)
void v_gemm(const u16* __restrict__ wvb, const u16* __restrict__ nx_t,
            const float* __restrict__ bv, u16* __restrict__ vbuf)
{
    int b = blockIdx.z;
    gemm_dev<128, 128, 1>(blockIdx.y * 128, blockIdx.x * 128,
                          wvb, nx_t + (size_t)b * N_ * C_, vbuf + (size_t)b * C_ * N_,
                          bv, nullptr, N_, C_, C_, C_, 1.f, nullptr);
}

// scores: P_partial[z][i][j] = exp(S - m_tile) bf16 + pstats.  grid (32,32,4)
__global__ __launch_bounds__(256)
void scores_gemm(const u16* __restrict__ q_t, const u16* __restrict__ k_t,
                 u16* __restrict__ S_bf, float2* __restrict__ pstats)
{
    int b = blockIdx.z;
    int i0 = blockIdx.y * 128, j0 = blockIdx.x * 128;
    float2* pst = pstats + ((size_t)b * N_ + i0) * 32 + blockIdx.x;
    gemm_dev<128, 128, 2>(i0, j0,
                          q_t + (size_t)b * N_ * C_, k_t + (size_t)b * N_ * C_,
                          S_bf + (size_t)b * N_ * N_, nullptr, nullptr, N_, C_, C_, C_,
                          0.044194173824159216f, pst);
}

// Combine partial stats -> sftab[b][jt][i] = exp(m_jt - m_glob) / l_glob.
// grid 64 x 256 (one thread per row).
__global__ __launch_bounds__(256)
void stats_combine(const float2* __restrict__ pstats, float* __restrict__ sftab)
{
    int r = blockIdx.x * 256 + threadIdx.x;    // global row b*N + i
    const float2* p = pstats + (size_t)r * 32;
    float m = -1e30f;
    #pragma unroll
    for (int jt = 0; jt < 32; ++jt) m = fmaxf(m, p[jt].x);
    float l = 0.f;
    #pragma unroll
    for (int jt = 0; jt < 32; ++jt) l += p[jt].y * __expf(p[jt].x - m);
    float inv = 1.f / l;
    int b = r >> 12, i = r & (N_ - 1);
    #pragma unroll
    for (int jt = 0; jt < 32; ++jt)
        sftab[((size_t)b * 32 + jt) * N_ + i] = __expf(p[jt].x - m) * inv;
}

// ---------------------------------------------------------------------------
// PV with two-level softmax fold: attn_t[i][c] = sum_jt sf[i][jt] *
//   sum_{j in jt} P_partial[i][j] * v[c][j].
// r5 pv structure (LDS staging, XOR swizzle, XCD-gather), BM=128 i, BN=64 c,
// BK=64. Temp accumulator per 128-wide jt folded into main acc with sf
// loaded PER C-FRAGMENT ROW (float4 at row (l>>4)*4 — fixes r7's fr-row bug).
// grid 1024 blocks.
// ---------------------------------------------------------------------------
__global__ __launch_bounds__(256)
void pv_part(const u16* __restrict__ S_bf, const float* __restrict__ sftab,
             const u16* __restrict__ vbuf, u16* __restrict__ attn_t)
{
    int id  = blockIdx.x;          // 0..1023
    int xcd = id & 7, slot = id >> 3;
    int yz  = xcd * 16 + (slot >> 3);   // (i-tile, b) combo, 0..127
    int ct  = slot & 7;                 // c-tile 0..7
    int it  = yz & 31, b = yz >> 5;
    const u16*   Pb  = S_bf + (size_t)b * N_ * N_;
    const float* sfb = sftab + (size_t)b * 32 * N_;
    const u16*   Vb  = vbuf + (size_t)b * C_ * N_;
    u16*         Ob  = attn_t + (size_t)b * N_ * C_;

    const int i0 = it * 128, c0 = ct * 64;
    const int t = threadIdx.x, l = t & 63, w = t >> 6;
    const int wr = w >> 1, wc = w & 1;       // WM=64, WN=32, MI=4, NI=2
    const int srow = l >> 3;
    const int sgr  = ((l & 7) ^ (l >> 3)) * 8;
    const int fr = l & 15, q = l >> 4;

    __shared__ u16 As[128 * 64];
    __shared__ u16 Bs[64 * 64];

    f32x4 accM[4][2], accT[4][2];
    #pragma unroll
    for (int a = 0; a < 4; ++a)
        #pragma unroll
        for (int b2 = 0; b2 < 2; ++b2) { accM[a][b2] = 0.f; accT[a][b2] = 0.f; }

    // C-fragment row base per mi: i0 + wr*64 + mi*16 + (l>>4)*4  (+e)
    const int crow0 = i0 + wr * 64 + (l >> 4) * 4;

    for (int jt = 0; jt < 32; ++jt) {
        // sf for the 4 C-rows of each mi fragment (float4, L2-resident table)
        f32x4 sfv[4];
        #pragma unroll
        for (int mi = 0; mi < 4; ++mi)
            sfv[mi] = *reinterpret_cast<const f32x4*>(
                &sfb[(size_t)jt * N_ + crow0 + mi * 16]);

        #pragma unroll
        for (int kk = 0; kk < 2; ++kk) {
            int k0 = jt * 128 + kk * 64;
            #pragma unroll
            for (int r = 0; r < 4; ++r) {
                int s = r * 4 + w;
                const u16* ga = Pb + (size_t)(i0 + s * 8 + srow) * N_ + (k0 + sgr);
                __builtin_amdgcn_global_load_lds(
                    (const __attribute__((address_space(1))) void*)ga,
                    (__attribute__((address_space(3))) void*)&As[s * 512], 16, 0, 0);
            }
            #pragma unroll
            for (int r = 0; r < 2; ++r) {
                int s = r * 4 + w;
                const u16* gb = Vb + (size_t)(c0 + s * 8 + srow) * N_ + (k0 + sgr);
                __builtin_amdgcn_global_load_lds(
                    (const __attribute__((address_space(1))) void*)gb,
                    (__attribute__((address_space(3))) void*)&Bs[s * 512], 16, 0, 0);
            }
            __syncthreads();
            #pragma unroll
            for (int h = 0; h < 2; ++h) {
                s16x8 af[4], bfr[2];
                #pragma unroll
                for (int mi = 0; mi < 4; ++mi) {
                    int r = wr * 64 + mi * 16 + fr;
                    int p = (h * 4 + q) ^ (r & 7);
                    af[mi] = *reinterpret_cast<const s16x8*>(&As[r * 64 + p * 8]);
                }
                #pragma unroll
                for (int ni = 0; ni < 2; ++ni) {
                    int r = wc * 32 + ni * 16 + fr;
                    int p = (h * 4 + q) ^ (r & 7);
                    bfr[ni] = *reinterpret_cast<const s16x8*>(&Bs[r * 64 + p * 8]);
                }
                #pragma unroll
                for (int mi = 0; mi < 4; ++mi)
                    #pragma unroll
                    for (int ni = 0; ni < 2; ++ni)
                        accT[mi][ni] = __builtin_amdgcn_mfma_f32_16x16x32_bf16(
                            af[mi], bfr[ni], accT[mi][ni], 0, 0, 0);
            }
            __syncthreads();
        }
        // fold jt's partial into main accumulator (exact fp32, per C-row sf)
        #pragma unroll
        for (int mi = 0; mi < 4; ++mi)
            #pragma unroll
            for (int ni = 0; ni < 2; ++ni) {
                accM[mi][ni] += accT[mi][ni] * sfv[mi];
                accT[mi][ni] = 0.f;
            }
    }

    const int orow = (l >> 4) * 4;
    const int ocol = l & 15;
    #pragma unroll
    for (int mi = 0; mi < 4; ++mi) {
        #pragma unroll
        for (int ni = 0; ni < 2; ++ni) {
            int ib = i0 + wr * 64 + mi * 16 + orow;
            int jb = c0 + wc * 32 + ni * 16 + ocol;
            #pragma unroll
            for (int e = 0; e < 4; ++e)
                Ob[(size_t)(ib + e) * C_ + jb] = f2bf(accM[mi][ni][e]);
        }
    }
}

// final: out[co][n] = x + bo[co] + sum_ci wo[co][ci]*attn_t[n][ci]. grid (32,4,4)
__global__ __launch_bounds__(256)
void final_gemm(const u16* __restrict__ wob, const u16* __restrict__ attn_t,
                const float* __restrict__ bo, const float* __restrict__ x,
                float* __restrict__ outp)
{
    int b = blockIdx.z;
    gemm_dev<128, 128, 3>(blockIdx.y * 128, blockIdx.x * 128,
                          wob, attn_t + (size_t)b * N_ * C_, outp + (size_t)b * C_ * N_,
                          bo, x + (size_t)b * C_ * N_, N_, C_, C_, C_, 1.f, nullptr);
}

// ---------------------------------------------------------------------------
extern "C" void kernel_launch(void* const* d_in, const int* in_sizes, int n_in,
                              void* d_out, int out_size, void* d_ws, size_t ws_size,
                              hipStream_t stream)
{
    const float* x     = (const float*)d_in[0];
    const float* gamma = (const float*)d_in[1];
    const float* beta  = (const float*)d_in[2];
    const float* wq    = (const float*)d_in[3];
    const float* bq    = (const float*)d_in[4];
    const float* wk    = (const float*)d_in[5];
    const float* bk    = (const float*)d_in[6];
    const float* wv    = (const float*)d_in[7];
    const float* bv    = (const float*)d_in[8];
    const float* wo    = (const float*)d_in[9];
    const float* bo    = (const float*)d_in[10];
    float* out = (float*)d_out;

    // Workspace carve (~277 MB total; r5 proved >= ~339 MB available).
    char* p = (char*)d_ws;
    auto take = [&](size_t bytes) { char* r = p; p += (bytes + 255) & ~(size_t)255; return r; };
    float* scale = (float*)take(B_ * C_ * 4);
    float* shift = (float*)take(B_ * C_ * 4);
    u16* wqb = (u16*)take((size_t)C_ * C_ * 2);
    u16* wkb = (u16*)take((size_t)C_ * C_ * 2);
    u16* wvb = (u16*)take((size_t)C_ * C_ * 2);
    u16* wob = (u16*)take((size_t)C_ * C_ * 2);
    u16* nx_t  = (u16*)take((size_t)B_ * N_ * C_ * 2);   // reused as attn_t
    u16* q_t   = (u16*)take((size_t)B_ * N_ * C_ * 2);
    u16* k_t   = (u16*)take((size_t)B_ * N_ * C_ * 2);
    u16* vbuf  = (u16*)take((size_t)B_ * C_ * N_ * 2);
    float2* pstats = (float2*)take((size_t)B_ * N_ * 32 * 8);   // 4 MB
    float*  sftab  = (float*)take((size_t)B_ * 32 * N_ * 4);    // 2 MB
    u16* S_bf = (u16*)take((size_t)B_ * N_ * N_ * 2);           // 134 MB
    u16* attn_t = nx_t;    // nx_t is dead after qkv projections

    gn_stats_kernel<<<128, 256, 0, stream>>>(x, gamma, beta, scale, shift);
    wcvt_kernel<<<256, 256, 0, stream>>>(wq, wk, wv, wo, wqb, wkb, wvb, wob);
    nxt_kernel<<<dim3(N_ / 64, C_ / 64, B_), 256, 0, stream>>>(x, scale, shift, nx_t);

    qk_gemm<<<dim3(C_ / 128, N_ / 128, 8), 256, 0, stream>>>(nx_t, wqb, wkb, bq, bk, q_t, k_t);
    v_gemm<<<dim3(N_ / 128, C_ / 128, B_), 256, 0, stream>>>(wvb, nx_t, bv, vbuf);

    scores_gemm<<<dim3(N_ / 128, N_ / 128, B_), 256, 0, stream>>>(q_t, k_t, S_bf, pstats);
    stats_combine<<<B_ * N_ / 256, 256, 0, stream>>>(pstats, sftab);
    pv_part<<<1024, 256, 0, stream>>>(S_bf, sftab, vbuf, attn_t);

    final_gemm<<<dim3(N_ / 128, C_ / 128, B_), 256, 0, stream>>>(wob, attn_t, bo, x, out);
}